// Round 1
// 405.530 us; speedup vs baseline: 1.0290x; 1.0290x over previous
//
#include <hip/hip_runtime.h>

typedef __bf16 bf16x8 __attribute__((ext_vector_type(8)));
typedef float floatx4 __attribute__((ext_vector_type(4)));
typedef float floatx2 __attribute__((ext_vector_type(2)));
typedef unsigned short ushortx8 __attribute__((ext_vector_type(8)));

__device__ __forceinline__ unsigned short f2b(float f) {
    union { float f; unsigned u; } v; v.f = f;
    unsigned r = v.u + 0x7fffu + ((v.u >> 16) & 1u);   // RNE
    return (unsigned short)(r >> 16);
}

// ---------------- CSR build ----------------

__global__ void deg_count_kernel(const int* __restrict__ dst, int* __restrict__ deg, int nE) {
    int e = blockIdx.x * blockDim.x + threadIdx.x;
    if (e < nE) atomicAdd(&deg[dst[e]], 1);
}

// hierarchical scan: 1024 elems per block
__global__ void scan1_kernel(const int* __restrict__ deg, int* __restrict__ bsum, int n) {
    __shared__ int s[256];
    int b = blockIdx.x, t = threadIdx.x;
    int base = b * 1024 + t * 4;
    int v = 0;
#pragma unroll
    for (int i = 0; i < 4; i++) { int idx = base + i; if (idx < n) v += deg[idx]; }
    s[t] = v; __syncthreads();
    for (int o = 128; o > 0; o >>= 1) { if (t < o) s[t] += s[t + o]; __syncthreads(); }
    if (t == 0) bsum[b] = s[0];
}

// scan3: per-block local scan; block base = sum of bsum[0..b) via in-block wave reduce (nb<=64)
__global__ void scan3_kernel(const int* __restrict__ deg, const int* __restrict__ bsum,
                             int* __restrict__ off, int n, int nb, int nE) {
    __shared__ int s[256];
    __shared__ int base_s;
    int b = blockIdx.x, t = threadIdx.x;
    if (t < 64) {
        int v = (t < nb && t < b) ? bsum[t] : 0;
        for (int o = 32; o > 0; o >>= 1) v += __shfl_down(v, o, 64);
        if (t == 0) base_s = v;
    }
    int idx = b * 1024 + t * 4;
    int a0 = (idx     < n) ? deg[idx]     : 0;
    int a1 = (idx + 1 < n) ? deg[idx + 1] : 0;
    int a2 = (idx + 2 < n) ? deg[idx + 2] : 0;
    int a3 = (idx + 3 < n) ? deg[idx + 3] : 0;
    int tsum = a0 + a1 + a2 + a3;
    s[t] = tsum; __syncthreads();
    for (int o = 1; o < 256; o <<= 1) {
        int u = (t >= o) ? s[t - o] : 0;
        __syncthreads();
        s[t] += u;
        __syncthreads();
    }
    int excl = s[t] - tsum + base_s;
    if (idx     < n) off[idx]     = excl;
    if (idx + 1 < n) off[idx + 1] = excl + a0;
    if (idx + 2 < n) off[idx + 2] = excl + a0 + a1;
    if (idx + 3 < n) off[idx + 3] = excl + a0 + a1 + a2;
    if (b == 0 && t == 0) off[n] = nE;
}

__global__ void fill_kernel(const int* __restrict__ src, const int* __restrict__ dst,
                            const int* __restrict__ off, int* __restrict__ cursor,
                            int* __restrict__ csr, int nE) {
    int e = blockIdx.x * blockDim.x + threadIdx.x;
    if (e < nE) {
        int d = dst[e];
        int pos = atomicAdd(&cursor[d], 1);
        csr[off[d] + pos] = src[e];
    }
}

// ---------------- fused conversions ----------------
// threads [0, Mpad*64): x -> bf16 A[:,512:1024] + fp8 X8 (pad rows zeroed)
// threads [Mpad*64, +65536): Wcat[o][k] = k<512 ? Wl[o][k] : Wr[o][k-512] (bf16)

__global__ void conv_kernel(const float* __restrict__ x, unsigned short* __restrict__ Abuf,
                            unsigned char* __restrict__ X8,
                            const float* __restrict__ Wl, const float* __restrict__ Wr,
                            unsigned short* __restrict__ Wcat,
                            int Mreal, long nx) {
    long t = (long)blockIdx.x * blockDim.x + threadIdx.x;
    if (t < nx) {
        long row = t >> 6;
        int c8 = (int)(t & 63) * 8;
        if (row < Mreal) {
            const float4* p4 = (const float4*)(x + row * 512 + c8);
            float4 v0 = p4[0], v1 = p4[1];
            ushortx8 o8;
            o8[0] = f2b(v0.x); o8[1] = f2b(v0.y); o8[2] = f2b(v0.z); o8[3] = f2b(v0.w);
            o8[4] = f2b(v1.x); o8[5] = f2b(v1.y); o8[6] = f2b(v1.z); o8[7] = f2b(v1.w);
            *(ushortx8*)(Abuf + row * 1024 + 512 + c8) = o8;
            unsigned int pa = __builtin_amdgcn_cvt_pk_fp8_f32(v0.x, v0.y, 0, false);
            pa = __builtin_amdgcn_cvt_pk_fp8_f32(v0.z, v0.w, pa, true);
            unsigned int pb = __builtin_amdgcn_cvt_pk_fp8_f32(v1.x, v1.y, 0, false);
            pb = __builtin_amdgcn_cvt_pk_fp8_f32(v1.z, v1.w, pb, true);
            *(uint2*)(X8 + row * 512 + c8) = make_uint2(pa, pb);
        } else {
            ushortx8 z = {0, 0, 0, 0, 0, 0, 0, 0};
            *(ushortx8*)(Abuf + row * 1024 + c8) = z;
            *(ushortx8*)(Abuf + row * 1024 + 512 + c8) = z;
        }
    } else {
        long u = t - nx;
        if (u >= 65536) return;
        int o = (int)(u >> 7);
        int c8 = (int)(u & 127) * 8;
        const float* p = (c8 < 512) ? (Wl + o * 512 + c8) : (Wr + o * 512 + (c8 - 512));
        float4 v0 = ((const float4*)p)[0], v1 = ((const float4*)p)[1];
        ushortx8 o8;
        o8[0] = f2b(v0.x); o8[1] = f2b(v0.y); o8[2] = f2b(v0.z); o8[3] = f2b(v0.w);
        o8[4] = f2b(v1.x); o8[5] = f2b(v1.y); o8[6] = f2b(v1.z); o8[7] = f2b(v1.w);
        *(ushortx8*)(Wcat + (long)o * 1024 + c8) = o8;
    }
}

// ---------------- aggregation: one wave per node, gathers fp8 x, mean -> bf16 A[:, 0:512] ----
// 4-deep rolling prefetch: keep 4 row-gathers in flight (was 1-deep -> serial-latency-bound)

__device__ __forceinline__ uint2 ldrow(const unsigned char* __restrict__ X8, int myi, int idx, int l) {
    int s = __builtin_amdgcn_readlane(myi, idx);
    return *(const uint2*)(X8 + (long)s * 512 + l * 8);
}

__device__ __forceinline__ void accum(float* a, uint2 p) {
    floatx2 f0 = __builtin_amdgcn_cvt_pk_f32_fp8(p.x, false);
    floatx2 f1 = __builtin_amdgcn_cvt_pk_f32_fp8(p.x, true);
    floatx2 f2 = __builtin_amdgcn_cvt_pk_f32_fp8(p.y, false);
    floatx2 f3 = __builtin_amdgcn_cvt_pk_f32_fp8(p.y, true);
    a[0] += f0[0]; a[1] += f0[1]; a[2] += f1[0]; a[3] += f1[1];
    a[4] += f2[0]; a[5] += f2[1]; a[6] += f3[0]; a[7] += f3[1];
}

__global__ void agg_kernel(const unsigned char* __restrict__ X8,
                           const int* __restrict__ off, const int* __restrict__ csr,
                           unsigned short* __restrict__ Abuf_w, int n) {
    int wid = (int)((blockIdx.x * (long)blockDim.x + threadIdx.x) >> 6);
    int l = threadIdx.x & 63;
    if (wid >= n) return;
    int beg = off[wid], end = off[wid + 1];
    float a[8] = {};
    int e = beg;
    while (e < end) {
        int cnt = end - e; if (cnt > 64) cnt = 64;
        int myi = csr[e + (l < cnt ? l : cnt - 1)];   // batch of up to 64 indices, one per lane
        int c1 = cnt - 1;
        uint2 b0 = ldrow(X8, myi, 0, l);
        uint2 b1 = ldrow(X8, myi, 1 < c1 ? 1 : c1, l);
        uint2 b2 = ldrow(X8, myi, 2 < c1 ? 2 : c1, l);
        uint2 b3 = ldrow(X8, myi, 3 < c1 ? 3 : c1, l);
        int j = 0;
        for (; j + 4 < cnt; j += 4) {
            uint2 n0 = ldrow(X8, myi, j + 4, l);
            uint2 n1 = ldrow(X8, myi, j + 5 < c1 ? j + 5 : c1, l);
            uint2 n2 = ldrow(X8, myi, j + 6 < c1 ? j + 6 : c1, l);
            uint2 n3 = ldrow(X8, myi, j + 7 < c1 ? j + 7 : c1, l);
            accum(a, b0); accum(a, b1); accum(a, b2); accum(a, b3);
            b0 = n0; b1 = n1; b2 = n2; b3 = n3;
        }
        int rem = cnt - j;   // 1..4, entries b0..b(rem-1) valid
        accum(a, b0);
        if (rem > 1) accum(a, b1);
        if (rem > 2) accum(a, b2);
        if (rem > 3) accum(a, b3);
        e += cnt;
    }
    int d = end - beg;
    float inv = 1.0f / (float)(d > 0 ? d : 1);
    ushortx8 o8;
#pragma unroll
    for (int i = 0; i < 8; i++) o8[i] = f2b(a[i] * inv);
    *(ushortx8*)(Abuf_w + (long)wid * 1024 + l * 8) = o8;
}

// ---------------- GEMM: out = A(Mx1024,bf16) . Wcat(512x1024,bf16)^T + bias ----------------
// T3-minimum 2-phase: explicit LDS double-buffer, stage(t+1) issued BEFORE compute(t),
// one __syncthreads per K-step (its vmcnt(0) drain lands after ~1000cyc of MFMA cover).
// T2: XOR chunk swizzle, both-sides (pre-swizzled global source, linear LDS dest,
// matching XOR on ds_read) -> 2-way max bank aliasing (free).
// XCD swizzle: the 4 col-blocks of one row-stripe land on the SAME XCD (L2 A-reuse)

__global__ __launch_bounds__(256, 3)
void gemm_kernel(const unsigned short* __restrict__ A, const unsigned short* __restrict__ B,
                 const float* __restrict__ bl, const int* __restrict__ deg,
                 float* __restrict__ out, int Mreal, int nby) {
    int L = blockIdx.x;
    int by = (L >> 5) * 8 + (L & 7);   // row-stripe
    int bx = (L >> 3) & 3;             // col-block: shares XCD (L%8) with its 3 siblings
    if (by >= nby) return;

    __shared__ unsigned short As[2][128 * 32];   // 2 x 8 KB, linear for global_load_lds
    __shared__ unsigned short Bs[2][128 * 32];
    int tid = threadIdx.x;
    int w = tid >> 6, l = tid & 63;
    long i0 = (long)by * 128;
    int n0 = bx * 128;
    int wm = (w >> 1) * 64, wn = (w & 1) * 64;
    int r = l & 15, q = l >> 4;
    int srow = l >> 2;                               // row within 16-row segment
    int cg8 = ((l & 3) ^ ((srow >> 1) & 3)) * 8;     // pre-swizzled source chunk (T2)
    int p8 = (q ^ ((r >> 1) & 3)) * 8;               // matching swizzled read chunk (T2)

    floatx4 acc[4][4] = {};

    auto stage = [&](int buf, int k0) {
#pragma unroll
        for (int j = 0; j < 2; j++) {
            int s = w * 2 + j;
            int row = s * 16 + srow;
            const unsigned short* ga = A + (i0 + row) * 1024 + k0 + cg8;
            const unsigned short* gb = B + (long)(n0 + row) * 1024 + k0 + cg8;
            __builtin_amdgcn_global_load_lds(
                (__attribute__((address_space(1))) void*)(uintptr_t)ga,
                (__attribute__((address_space(3))) void*)(uintptr_t)(&As[buf][s * 512]), 16, 0, 0);
            __builtin_amdgcn_global_load_lds(
                (__attribute__((address_space(1))) void*)(uintptr_t)gb,
                (__attribute__((address_space(3))) void*)(uintptr_t)(&Bs[buf][s * 512]), 16, 0, 0);
        }
    };

    stage(0, 0);
    __syncthreads();

    for (int t = 0; t < 32; t++) {
        int cur = t & 1;
        if (t < 31) stage(cur ^ 1, (t + 1) * 32);   // issue next-tile loads FIRST
        bf16x8 af[4], bfr[4];
#pragma unroll
        for (int a = 0; a < 4; a++)
            af[a] = *(const bf16x8*)(&As[cur][(wm + a * 16 + r) * 32 + p8]);
#pragma unroll
        for (int b = 0; b < 4; b++)
            bfr[b] = *(const bf16x8*)(&Bs[cur][(wn + b * 16 + r) * 32 + p8]);
#pragma unroll
        for (int a = 0; a < 4; a++)
#pragma unroll
            for (int b = 0; b < 4; b++)
                acc[a][b] = __builtin_amdgcn_mfma_f32_16x16x32_bf16(af[a], bfr[b], acc[a][b], 0, 0, 0);
        __syncthreads();   // drains vmcnt(0): next buffer ready; cur reads done before overwrite
    }

#pragma unroll
    for (int a = 0; a < 4; a++) {
        long rb = i0 + wm + a * 16 + q * 4;
#pragma unroll
        for (int rr = 0; rr < 4; rr++) {
            long row = rb + rr;
            if (row < Mreal) {
                bool hasdeg = deg[row] > 0;
#pragma unroll
                for (int b = 0; b < 4; b++) {
                    int col = n0 + wn + b * 16 + r;
                    float v = acc[a][b][rr];
                    if (hasdeg) v += bl[col];
                    out[row * 512 + col] = v;
                }
            }
        }
    }
}

// ---------------- launch ----------------

extern "C" void kernel_launch(void* const* d_in, const int* in_sizes, int n_in,
                              void* d_out, int out_size, void* d_ws, size_t ws_size,
                              hipStream_t stream) {
    const float* x  = (const float*)d_in[0];
    const int* eidx = (const int*)d_in[1];
    const float* Wl = (const float*)d_in[2];
    const float* bl = (const float*)d_in[3];
    const float* Wr = (const float*)d_in[4];
    float* out = (float*)d_out;

    int N  = in_sizes[0] / 512;
    int nE = in_sizes[1] / 2;
    const int* src = eidx;
    const int* dst = eidx + nE;
    int Mpad = (N + 127) & ~127;
    int nb = (N + 1023) / 1024;
    int nby = Mpad / 128;

    char* w = (char*)d_ws;
    size_t o = 0;
    auto alloc = [&](size_t bytes) { void* p = w + o; o = (o + bytes + 255) & ~255UL; return p; };
    int* deg    = (int*)alloc((size_t)N * 4);
    int* cursor = (int*)alloc((size_t)N * 4);
    int* off    = (int*)alloc((size_t)(N + 1) * 4);
    int* bsum   = (int*)alloc((size_t)nb * 4);
    int* csr    = (int*)alloc((size_t)nE * 4);
    unsigned short* Wcat = (unsigned short*)alloc((size_t)512 * 1024 * 2);
    unsigned short* Abuf = (unsigned short*)alloc((size_t)Mpad * 1024 * 2);
    unsigned char*  X8   = (unsigned char*)alloc((size_t)Mpad * 512);
    if (o > ws_size) return;   // workspace too small -> validation will flag

    hipMemsetAsync(deg, 0, (size_t)N * 4, stream);
    hipMemsetAsync(cursor, 0, (size_t)N * 4, stream);

    deg_count_kernel<<<(nE + 255) / 256, 256, 0, stream>>>(dst, deg, nE);
    scan1_kernel<<<nb, 256, 0, stream>>>(deg, bsum, N);
    scan3_kernel<<<nb, 256, 0, stream>>>(deg, bsum, off, N, nb, nE);
    fill_kernel<<<(nE + 255) / 256, 256, 0, stream>>>(src, dst, off, cursor, csr, nE);
    long nx = (long)Mpad * 64;
    conv_kernel<<<(int)((nx + 65536 + 255) / 256), 256, 0, stream>>>(x, Abuf, X8, Wl, Wr, Wcat, N, nx);
    agg_kernel<<<(N * 64 + 255) / 256, 256, 0, stream>>>(X8, off, csr, Abuf, N);

    int nbyp = (nby + 7) & ~7;
    gemm_kernel<<<nbyp * 4, 256, 0, stream>>>(Abuf, Wcat, bl, deg, out, N, nby);
}

// Round 2
// 393.769 us; speedup vs baseline: 1.0597x; 1.0299x over previous
//
#include <hip/hip_runtime.h>

typedef __bf16 bf16x8 __attribute__((ext_vector_type(8)));
typedef float floatx4 __attribute__((ext_vector_type(4)));
typedef float floatx2 __attribute__((ext_vector_type(2)));
typedef unsigned short ushortx8 __attribute__((ext_vector_type(8)));

__device__ __forceinline__ unsigned short f2b(float f) {
    union { float f; unsigned u; } v; v.f = f;
    unsigned r = v.u + 0x7fffu + ((v.u >> 16) & 1u);   // RNE
    return (unsigned short)(r >> 16);
}

// ---------------- CSR build ----------------

// hierarchical scan: 1024 elems per block
__global__ void scan1_kernel(const int* __restrict__ deg, int* __restrict__ bsum, int n) {
    __shared__ int s[256];
    int b = blockIdx.x, t = threadIdx.x;
    int base = b * 1024 + t * 4;
    int v = 0;
#pragma unroll
    for (int i = 0; i < 4; i++) { int idx = base + i; if (idx < n) v += deg[idx]; }
    s[t] = v; __syncthreads();
    for (int o = 128; o > 0; o >>= 1) { if (t < o) s[t] += s[t + o]; __syncthreads(); }
    if (t == 0) bsum[b] = s[0];
}

// scan3: per-block local scan; block base = sum of bsum[0..b) via in-block wave reduce (nb<=64)
__global__ void scan3_kernel(const int* __restrict__ deg, const int* __restrict__ bsum,
                             int* __restrict__ off, int n, int nb, int nE) {
    __shared__ int s[256];
    __shared__ int base_s;
    int b = blockIdx.x, t = threadIdx.x;
    if (t < 64) {
        int v = (t < nb && t < b) ? bsum[t] : 0;
        for (int o = 32; o > 0; o >>= 1) v += __shfl_down(v, o, 64);
        if (t == 0) base_s = v;
    }
    int idx = b * 1024 + t * 4;
    int a0 = (idx     < n) ? deg[idx]     : 0;
    int a1 = (idx + 1 < n) ? deg[idx + 1] : 0;
    int a2 = (idx + 2 < n) ? deg[idx + 2] : 0;
    int a3 = (idx + 3 < n) ? deg[idx + 3] : 0;
    int tsum = a0 + a1 + a2 + a3;
    s[t] = tsum; __syncthreads();
    for (int o = 1; o < 256; o <<= 1) {
        int u = (t >= o) ? s[t - o] : 0;
        __syncthreads();
        s[t] += u;
        __syncthreads();
    }
    int excl = s[t] - tsum + base_s;
    if (idx     < n) off[idx]     = excl;
    if (idx + 1 < n) off[idx + 1] = excl + a0;
    if (idx + 2 < n) off[idx + 2] = excl + a0 + a1;
    if (idx + 3 < n) off[idx + 3] = excl + a0 + a1 + a2;
    if (b == 0 && t == 0) off[n] = nE;
}

__global__ void fill_kernel(const int* __restrict__ src, const int* __restrict__ dst,
                            const int* __restrict__ off, int* __restrict__ cursor,
                            int* __restrict__ csr, int nE) {
    int e = blockIdx.x * blockDim.x + threadIdx.x;
    if (e < nE) {
        int d = dst[e];
        int pos = atomicAdd(&cursor[d], 1);
        csr[off[d] + pos] = src[e];
    }
}

// ---------------- fused conversions + degree count ----------------
// threads [0, Mpad*64): x -> bf16 A[:,512:1024] + fp8 X8 (pad rows zeroed)
// threads [Mpad*64, +65536): Wcat[o][k] = k<512 ? Wl[o][k] : Wr[o][k-512] (bf16)
// threads [Mpad*64+65536, +nE): deg atomics (fused: overlaps streaming with atomic pipe)

__global__ void conv_kernel(const float* __restrict__ x, unsigned short* __restrict__ Abuf,
                            unsigned char* __restrict__ X8,
                            const float* __restrict__ Wl, const float* __restrict__ Wr,
                            unsigned short* __restrict__ Wcat,
                            const int* __restrict__ dst, int* __restrict__ deg, int nE,
                            int Mreal, long nx) {
    long t = (long)blockIdx.x * blockDim.x + threadIdx.x;
    if (t < nx) {
        long row = t >> 6;
        int c8 = (int)(t & 63) * 8;
        if (row < Mreal) {
            const float4* p4 = (const float4*)(x + row * 512 + c8);
            float4 v0 = p4[0], v1 = p4[1];
            ushortx8 o8;
            o8[0] = f2b(v0.x); o8[1] = f2b(v0.y); o8[2] = f2b(v0.z); o8[3] = f2b(v0.w);
            o8[4] = f2b(v1.x); o8[5] = f2b(v1.y); o8[6] = f2b(v1.z); o8[7] = f2b(v1.w);
            *(ushortx8*)(Abuf + row * 1024 + 512 + c8) = o8;
            unsigned int pa = __builtin_amdgcn_cvt_pk_fp8_f32(v0.x, v0.y, 0, false);
            pa = __builtin_amdgcn_cvt_pk_fp8_f32(v0.z, v0.w, pa, true);
            unsigned int pb = __builtin_amdgcn_cvt_pk_fp8_f32(v1.x, v1.y, 0, false);
            pb = __builtin_amdgcn_cvt_pk_fp8_f32(v1.z, v1.w, pb, true);
            *(uint2*)(X8 + row * 512 + c8) = make_uint2(pa, pb);
        } else {
            ushortx8 z = {0, 0, 0, 0, 0, 0, 0, 0};
            *(ushortx8*)(Abuf + row * 1024 + c8) = z;
            *(ushortx8*)(Abuf + row * 1024 + 512 + c8) = z;
        }
    } else {
        long u = t - nx;
        if (u < 65536) {
            int o = (int)(u >> 7);
            int c8 = (int)(u & 127) * 8;
            const float* p = (c8 < 512) ? (Wl + o * 512 + c8) : (Wr + o * 512 + (c8 - 512));
            float4 v0 = ((const float4*)p)[0], v1 = ((const float4*)p)[1];
            ushortx8 o8;
            o8[0] = f2b(v0.x); o8[1] = f2b(v0.y); o8[2] = f2b(v0.z); o8[3] = f2b(v0.w);
            o8[4] = f2b(v1.x); o8[5] = f2b(v1.y); o8[6] = f2b(v1.z); o8[7] = f2b(v1.w);
            *(ushortx8*)(Wcat + (long)o * 1024 + c8) = o8;
        } else {
            long v = u - 65536;
            if (v < nE) atomicAdd(&deg[dst[v]], 1);
        }
    }
}

// ---------------- aggregation: one wave per node, gathers fp8 x, mean -> bf16 A[:, 0:512] ----
// 4-deep rolling prefetch: keep 4 row-gathers in flight

__device__ __forceinline__ uint2 ldrow(const unsigned char* __restrict__ X8, int myi, int idx, int l) {
    int s = __builtin_amdgcn_readlane(myi, idx);
    return *(const uint2*)(X8 + (long)s * 512 + l * 8);
}

__device__ __forceinline__ void accum(float* a, uint2 p) {
    floatx2 f0 = __builtin_amdgcn_cvt_pk_f32_fp8(p.x, false);
    floatx2 f1 = __builtin_amdgcn_cvt_pk_f32_fp8(p.x, true);
    floatx2 f2 = __builtin_amdgcn_cvt_pk_f32_fp8(p.y, false);
    floatx2 f3 = __builtin_amdgcn_cvt_pk_f32_fp8(p.y, true);
    a[0] += f0[0]; a[1] += f0[1]; a[2] += f1[0]; a[3] += f1[1];
    a[4] += f2[0]; a[5] += f2[1]; a[6] += f3[0]; a[7] += f3[1];
}

__global__ void agg_kernel(const unsigned char* __restrict__ X8,
                           const int* __restrict__ off, const int* __restrict__ csr,
                           unsigned short* __restrict__ Abuf_w, int n) {
    int wid = (int)((blockIdx.x * (long)blockDim.x + threadIdx.x) >> 6);
    int l = threadIdx.x & 63;
    if (wid >= n) return;
    int beg = off[wid], end = off[wid + 1];
    float a[8] = {};
    int e = beg;
    while (e < end) {
        int cnt = end - e; if (cnt > 64) cnt = 64;
        int myi = csr[e + (l < cnt ? l : cnt - 1)];   // batch of up to 64 indices, one per lane
        int c1 = cnt - 1;
        uint2 b0 = ldrow(X8, myi, 0, l);
        uint2 b1 = ldrow(X8, myi, 1 < c1 ? 1 : c1, l);
        uint2 b2 = ldrow(X8, myi, 2 < c1 ? 2 : c1, l);
        uint2 b3 = ldrow(X8, myi, 3 < c1 ? 3 : c1, l);
        int j = 0;
        for (; j + 4 < cnt; j += 4) {
            uint2 n0 = ldrow(X8, myi, j + 4, l);
            uint2 n1 = ldrow(X8, myi, j + 5 < c1 ? j + 5 : c1, l);
            uint2 n2 = ldrow(X8, myi, j + 6 < c1 ? j + 6 : c1, l);
            uint2 n3 = ldrow(X8, myi, j + 7 < c1 ? j + 7 : c1, l);
            accum(a, b0); accum(a, b1); accum(a, b2); accum(a, b3);
            b0 = n0; b1 = n1; b2 = n2; b3 = n3;
        }
        int rem = cnt - j;   // 1..4, entries b0..b(rem-1) valid
        accum(a, b0);
        if (rem > 1) accum(a, b1);
        if (rem > 2) accum(a, b2);
        if (rem > 3) accum(a, b3);
        e += cnt;
    }
    int d = end - beg;
    float inv = 1.0f / (float)(d > 0 ? d : 1);
    ushortx8 o8;
#pragma unroll
    for (int i = 0; i < 8; i++) o8[i] = f2b(a[i] * inv);
    *(ushortx8*)(Abuf_w + (long)wid * 1024 + l * 8) = o8;
}

// ---------------- GEMM: out = A(Mx1024,bf16) . Wcat(512x1024,bf16)^T + bias ----------------
// T4 counted-vmcnt 3-buffer pipeline (depth-2 prefetch):
//   iter t: s_waitcnt vmcnt(4)  [tile t landed; tile t+1's 4 loads STAY in flight across barrier]
//           raw s_barrier       [no compiler vmcnt(0) drain -- this was the 2-phase stall]
//           stage tile t+2 into buf (t+2)%3   [overwrites buf t-1: its ds_reads were
//                                              lgkmcnt-drained before anyone passed barrier(t)]
//           ds_read buf t, MFMA (setprio-wrapped, T5)
// T2 XOR chunk swizzle both-sides (pre-swizzled global src + matching read XOR).
// MFMA operands SWAPPED (computes C via B^T convention): lane holds 4 consecutive cols
// -> float4 epilogue stores (16 dwordx4 vs 64 scalar dwords).
// XCD swizzle: the 4 col-blocks of one row-stripe share an XCD (L2 A-reuse).

__global__ __launch_bounds__(256, 3)
void gemm_kernel(const unsigned short* __restrict__ A, const unsigned short* __restrict__ B,
                 const float* __restrict__ bl, const int* __restrict__ deg,
                 float* __restrict__ out, int Mreal, int nby) {
    int L = blockIdx.x;
    int by = (L >> 5) * 8 + (L & 7);   // row-stripe
    int bx = (L >> 3) & 3;             // col-block: shares XCD (L%8) with its 3 siblings
    if (by >= nby) return;             // whole block returns: barrier-uniform

    __shared__ unsigned short As[3 * 128 * 32];   // 3 x 8 KB
    __shared__ unsigned short Bs[3 * 128 * 32];   // total 48 KB -> 3 blocks/CU
    int tid = threadIdx.x;
    int w = tid >> 6, l = tid & 63;
    long i0 = (long)by * 128;
    int n0 = bx * 128;
    int wm = (w >> 1) * 64, wn = (w & 1) * 64;
    int r = l & 15, q = l >> 4;
    int srow = l >> 2;                               // row within 16-row segment
    int cg8 = ((l & 3) ^ ((srow >> 1) & 3)) * 8;     // pre-swizzled source chunk (T2)
    int p8 = (q ^ ((r >> 1) & 3)) * 8;               // matching swizzled read chunk (T2)

    floatx4 acc[4][4] = {};

    auto stage = [&](int buf, int k0) {
#pragma unroll
        for (int j = 0; j < 2; j++) {
            int s = w * 2 + j;
            int row = s * 16 + srow;
            const unsigned short* ga = A + (i0 + row) * 1024 + k0 + cg8;
            const unsigned short* gb = B + (long)(n0 + row) * 1024 + k0 + cg8;
            __builtin_amdgcn_global_load_lds(
                (__attribute__((address_space(1))) void*)(uintptr_t)ga,
                (__attribute__((address_space(3))) void*)(uintptr_t)(As + buf * 4096 + s * 512), 16, 0, 0);
            __builtin_amdgcn_global_load_lds(
                (__attribute__((address_space(1))) void*)(uintptr_t)gb,
                (__attribute__((address_space(3))) void*)(uintptr_t)(Bs + buf * 4096 + s * 512), 16, 0, 0);
        }
    };

    auto compute = [&](int cur) {
        bf16x8 af[4], bfr[4];
        const unsigned short* Ab = As + cur * 4096;
        const unsigned short* Bb = Bs + cur * 4096;
#pragma unroll
        for (int a = 0; a < 4; a++)
            af[a] = *(const bf16x8*)(Ab + (wm + a * 16 + r) * 32 + p8);
#pragma unroll
        for (int b = 0; b < 4; b++)
            bfr[b] = *(const bf16x8*)(Bb + (wn + b * 16 + r) * 32 + p8);
        __builtin_amdgcn_s_setprio(1);
#pragma unroll
        for (int a = 0; a < 4; a++)
#pragma unroll
            for (int b = 0; b < 4; b++)
                acc[a][b] = __builtin_amdgcn_mfma_f32_16x16x32_bf16(bfr[b], af[a], acc[a][b], 0, 0, 0);
        __builtin_amdgcn_s_setprio(0);
    };

    stage(0, 0);
    stage(1, 32);
    int cur = 0;
    for (int t = 0; t < 31; ++t) {
        asm volatile("s_waitcnt vmcnt(4)" ::: "memory");   // tile t done; t+1 in flight
        __builtin_amdgcn_sched_barrier(0);
        __builtin_amdgcn_s_barrier();                      // raw: no vmcnt(0) drain
        __builtin_amdgcn_sched_barrier(0);
        if (t + 2 < 32) {
            int nb2 = cur + 2; if (nb2 >= 3) nb2 -= 3;
            stage(nb2, (t + 2) * 32);
        }
        compute(cur);
        cur++; if (cur >= 3) cur -= 3;
    }
    // last tile: everything must be drained
    asm volatile("s_waitcnt vmcnt(0)" ::: "memory");
    __builtin_amdgcn_sched_barrier(0);
    __builtin_amdgcn_s_barrier();
    __builtin_amdgcn_sched_barrier(0);
    compute(cur);

    // epilogue: lane (q,r) holds, for acc[a][b]: row = wm+a*16+r, cols = wn+b*16+q*4+{0..3}
#pragma unroll
    for (int a = 0; a < 4; a++) {
        long row = i0 + wm + a * 16 + r;
        if (row < Mreal) {
            bool hasdeg = deg[row] > 0;
#pragma unroll
            for (int b = 0; b < 4; b++) {
                int col0 = n0 + wn + b * 16 + q * 4;
                floatx4 v = acc[a][b];
                if (hasdeg) {
                    float4 bb = *(const float4*)(bl + col0);
                    v[0] += bb.x; v[1] += bb.y; v[2] += bb.z; v[3] += bb.w;
                }
                *(floatx4*)(out + row * 512 + col0) = v;
            }
        }
    }
}

// ---------------- launch ----------------

extern "C" void kernel_launch(void* const* d_in, const int* in_sizes, int n_in,
                              void* d_out, int out_size, void* d_ws, size_t ws_size,
                              hipStream_t stream) {
    const float* x  = (const float*)d_in[0];
    const int* eidx = (const int*)d_in[1];
    const float* Wl = (const float*)d_in[2];
    const float* bl = (const float*)d_in[3];
    const float* Wr = (const float*)d_in[4];
    float* out = (float*)d_out;

    int N  = in_sizes[0] / 512;
    int nE = in_sizes[1] / 2;
    const int* src = eidx;
    const int* dst = eidx + nE;
    int Mpad = (N + 127) & ~127;
    int nb = (N + 1023) / 1024;
    int nby = Mpad / 128;

    char* w = (char*)d_ws;
    size_t o = 0;
    auto alloc = [&](size_t bytes) { void* p = w + o; o = (o + bytes + 255) & ~255UL; return p; };
    int* deg    = (int*)alloc((size_t)N * 4);
    int* cursor = (int*)alloc((size_t)N * 4);
    int* off    = (int*)alloc((size_t)(N + 1) * 4);
    int* bsum   = (int*)alloc((size_t)nb * 4);
    int* csr    = (int*)alloc((size_t)nE * 4);
    unsigned short* Wcat = (unsigned short*)alloc((size_t)512 * 1024 * 2);
    unsigned short* Abuf = (unsigned short*)alloc((size_t)Mpad * 1024 * 2);
    unsigned char*  X8   = (unsigned char*)alloc((size_t)Mpad * 512);
    if (o > ws_size) return;   // workspace too small -> validation will flag

    hipMemsetAsync(deg, 0, (size_t)N * 4, stream);
    hipMemsetAsync(cursor, 0, (size_t)N * 4, stream);

    long nx = (long)Mpad * 64;
    long ntot = nx + 65536 + nE;
    conv_kernel<<<(int)((ntot + 255) / 256), 256, 0, stream>>>(x, Abuf, X8, Wl, Wr, Wcat,
                                                               dst, deg, nE, N, nx);
    scan1_kernel<<<nb, 256, 0, stream>>>(deg, bsum, N);
    scan3_kernel<<<nb, 256, 0, stream>>>(deg, bsum, off, N, nb, nE);
    fill_kernel<<<(nE + 255) / 256, 256, 0, stream>>>(src, dst, off, cursor, csr, nE);
    agg_kernel<<<(N * 64 + 255) / 256, 256, 0, stream>>>(X8, off, csr, Abuf, N);

    int nbyp = (nby + 7) & ~7;
    gemm_kernel<<<nbyp * 4, 256, 0, stream>>>(Abuf, Wcat, bl, deg, out, N, nby);
}